// Round 9
// baseline (9296.470 us; speedup 1.0000x reference)
//
#include <hip/hip_runtime.h>

// Farthest Point Sampling: points (B, N, 3) fp32 -> indices (B, M) int32.
// B=16, N=65536, M=2048.  Reference semantics (locked in R2, absmax=0):
// float64 pipeline: dx=(double)x-(double)cx; d=((dx*dx+dy*dy)+dz*dz) with
// separate rounding (no FMA); min via fmin; argmax first-index tie-break
// (u64 bit-compare == f64 compare for nonneg values; verified R8).
//
// Round 9: collapse the intra-block serial tail. R8 falsified the downclock
// theory (heaters doubled VALUBusy, duration unchanged) -> the 2.85 us/iter
// is real chain latency. R6 spent ~1 us/iter on: second __syncthreads, two
// LDS round-trips (wave winners + s_c broadcast), and a wave0-serialized
// final reduce. New structure (one sync per iteration):
//   compute -> 6-stage wave butterfly -> wave winner to LDS[parity]
//   -> sync -> EVERY wave redundantly reduces the 8 winners (3 stages)
//   -> wave0/lane0 publishes -> EVERY wave polls the 16 slots itself,
//      reduces (4 stages), pulls winner coords into REGISTERS by shuffle.
// No second sync, no s_c. LDS winner buffer double-buffered by parity; a
// wave reaches write m+2 only after its block published m+1, which required
// sync m+1, which proves all waves finished reading buffer m => no race.
//
// Barrier protocol (unchanged from R6): 4 self-tagged 8-B relaxed atomic
// words per 128-B slot, per (parity, batch, rank):
//   A = value_lo32<<32 | m<<16 | idx        (idx<65536, m<2048: 16b each)
//   B = value_hi32<<32 | m<<16 | idx
//   C = x_bits<<32     | m<<16 | y_hi16
//   D = y_lo16<<48     | z_bits<<16 | m
// Aligned 8-B stores are single-copy atomic; every word carries m => torn
// epochs are detected and re-polled. No fences anywhere. Slot rewritten at
// m+2 only after its writer saw all tags m+1, which post only after every
// block's every wave finished reading m. 0xAA poison tag = 0xAAAA != any
// m in [1,2048) => no init kernel.

#define N_PTS   65536
#define M_SAMP  2048
#define NT      512
#define BPB     16                  // blocks per batch
#define PTS_BLK (N_PTS / BPB)       // 4096
#define PPT     (PTS_BLK / NT)      // 8 points per thread
#define NWAVES  (NT / 64)           // 8
#define NBATCH  16
#define SLOT_U64 16                 // 128 B per slot

typedef unsigned long long u64;

__device__ __forceinline__ u64 ld_agent(const u64* a) {
  return __hip_atomic_load(a, __ATOMIC_RELAXED, __HIP_MEMORY_SCOPE_AGENT);
}
__device__ __forceinline__ void st_agent(u64* a, u64 v) {
  __hip_atomic_store(a, v, __ATOMIC_RELAXED, __HIP_MEMORY_SCOPE_AGENT);
}

__global__ __launch_bounds__(NT, 2)
void fps_multi(const float* __restrict__ pts, int* __restrict__ out,
               u64* __restrict__ ws) {
  const int rank = blockIdx.x & (BPB - 1);     // R6 linear order: id = b*16+rank
  const int b    = blockIdx.x >> 4;
  const float* __restrict__ p = pts + (size_t)b * (size_t)(N_PTS * 3);
  int* __restrict__ o = out + (size_t)b * M_SAMP;
  const int t    = threadIdx.x;
  const int lane = t & 63;
  const int wave = t >> 6;
  const int base = rank * PTS_BLK;

  __shared__ float s_pts[PTS_BLK * 3];         // 48 KB slice
  __shared__ u64   s_wv[2][NWAVES];            // wave winners, parity-buffered
  __shared__ int   s_wi[2][NWAVES];

  for (int i = t; i < PTS_BLK * 3; i += NT)
    s_pts[i] = p[base * 3 + i];
  if (rank == 0 && t == 0) o[0] = 0;
  // Seed centroid (point 0) straight into registers — s_c is gone.
  float c0 = p[0], c1 = p[1], c2 = p[2];
  __syncthreads();

  // Own points pre-converted to f64; (double)x is exact.
  double pd[PPT][3];
  double md[PPT];
#pragma unroll
  for (int j = 0; j < PPT; ++j) {
    const int l = t + j * NT;
    pd[j][0] = (double)s_pts[3 * l + 0];
    pd[j][1] = (double)s_pts[3 * l + 1];
    pd[j][2] = (double)s_pts[3 * l + 2];
    md[j] = 1e10;
  }

  for (int m = 1; m < M_SAMP; ++m) {
    const double cx = (double)c0;
    const double cy = (double)c1;
    const double cz = (double)c2;

    u64 bestb = 0;              // loses to any d>0; ties at +0 resolved by idx
    int besti = base + t;

    // Indices base + t + j*NT ascend with j => strict '>' keeps the first
    // (lowest-index) maximum within a thread.
#pragma unroll
    for (int j = 0; j < PPT; ++j) {
      const double dx = __dsub_rn(pd[j][0], cx);
      const double dy = __dsub_rn(pd[j][1], cy);
      const double dz = __dsub_rn(pd[j][2], cz);
      const double d  = __dadd_rn(__dadd_rn(__dmul_rn(dx, dx),
                                            __dmul_rn(dy, dy)),
                                  __dmul_rn(dz, dz));
      const double nmd = fmin(md[j], d);
      md[j] = nmd;
      const u64 nb = (u64)__double_as_longlong(nmd);
      if (nb > bestb) { bestb = nb; besti = base + t + j * NT; }
    }

    // 64-lane butterfly argmax (u64 compare), min-index tie-break.
#pragma unroll
    for (int off = 32; off >= 1; off >>= 1) {
      const u64 ov = __shfl_xor(bestb, off, 64);
      const int oi = __shfl_xor(besti, off, 64);
      if (ov > bestb || (ov == bestb && oi < besti)) { bestb = ov; besti = oi; }
    }

    const int par = m & 1;
    if (lane == 0) { s_wv[par][wave] = bestb; s_wi[par][wave] = besti; }
    __syncthreads();            // the ONLY barrier in the loop

    // Every wave redundantly reduces the 8 wave winners (3 parallel stages).
    u64 bb; int bi;
    if (lane < NWAVES) { bb = s_wv[par][lane]; bi = s_wi[par][lane]; }
    else               { bb = 0;               bi = 0x7FFFFFFF; }
#pragma unroll
    for (int off = NWAVES / 2; off >= 1; off >>= 1) {
      const u64 ov = __shfl_xor(bb, off, 64);
      const int oi = __shfl_xor(bi, off, 64);
      if (ov > bb || (ov == bb && oi < bi)) { bb = ov; bi = oi; }
    }
    // Lanes 0..7 of every wave now hold the block winner.

    const u64 mm  = (u64)(unsigned)m;
    const u64 grp = (u64)((par * NBATCH + b) * BPB);
    if (t == 0) {               // wave 0, lane 0 publishes
      u64* slot = ws + (grp + rank) * SLOT_U64;
      const int l = bi - base;  // block winner lies in our slice
      const unsigned xb = __float_as_uint(s_pts[3 * l + 0]);
      const unsigned yb = __float_as_uint(s_pts[3 * l + 1]);
      const unsigned zb = __float_as_uint(s_pts[3 * l + 2]);
      const u64 ti = (mm << 16) | (u64)(unsigned)bi;
      st_agent(&slot[0], (bb << 32) | ti);                        // A
      st_agent(&slot[1], (bb & 0xFFFFFFFF00000000ull) | ti);      // B
      st_agent(&slot[2], ((u64)xb << 32) | (mm << 16) | (u64)(yb >> 16));        // C
      st_agent(&slot[3], ((u64)(yb & 0xFFFFu) << 48) | ((u64)zb << 16) | mm);    // D
    }

    // EVERY wave polls the 16 slots and reduces; result lands in registers.
    float fx = 0.0f, fy = 0.0f, fz = 0.0f;
    int   wi = 0;
    if (lane < BPB) {
      const u64* rs = ws + (grp + lane) * SLOT_U64;
      u64 A, B, C, D;
      for (;;) {
        A = ld_agent(rs + 0);
        B = ld_agent(rs + 1);
        C = ld_agent(rs + 2);
        D = ld_agent(rs + 3);
        const bool ok = (((A >> 16) & 0xFFFFull) == mm) &
                        (((B >> 16) & 0xFFFFull) == mm) &
                        (((C >> 16) & 0xFFFFull) == mm) &
                        ((D & 0xFFFFull) == mm);
        if (ok) break;
      }
      u64 v = (B & 0xFFFFFFFF00000000ull) | (A >> 32);   // f64 bits
      int i = (int)(A & 0xFFFFull);
      float gx = __uint_as_float((unsigned)(C >> 32));
      float gy = __uint_as_float((unsigned)(((C & 0xFFFFull) << 16) | (D >> 48)));
      float gz = __uint_as_float((unsigned)((D >> 16) & 0xFFFFFFFFull));
      int r = lane;                           // contributing rank
#pragma unroll
      for (int off = BPB / 2; off >= 1; off >>= 1) {
        const u64 ov = __shfl_xor(v, off, 64);
        const int oi = __shfl_xor(i, off, 64);
        const int orr = __shfl_xor(r, off, 64);
        if (ov > v || (ov == v && oi < i)) { v = ov; i = oi; r = orr; }
      }
      // Lanes 0..15 agree on winner rank r; pull its coords (r < 16 active).
      fx = __shfl(gx, r, 64);
      fy = __shfl(gy, r, 64);
      fz = __shfl(gz, r, 64);
      wi = i;
    }
    // Whole-wave broadcast from lane 0 — centroid stays in registers.
    fx = __shfl(fx, 0, 64);
    fy = __shfl(fy, 0, 64);
    fz = __shfl(fz, 0, 64);
    c0 = fx; c1 = fy; c2 = fz;
    if (rank == 0 && t == 0) o[m] = wi;
  }
}

extern "C" void kernel_launch(void* const* d_in, const int* in_sizes, int n_in,
                              void* d_out, int out_size, void* d_ws, size_t ws_size,
                              hipStream_t stream) {
  const float* pts = (const float*)d_in[0];
  int* out = (int*)d_out;
  // ws usage: 2 * 16 * 16 slots * 128 B = 64 KB.
  hipLaunchKernelGGL(fps_multi, dim3(BPB * NBATCH), dim3(NT), 0, stream,
                     pts, out, (u64*)d_ws);
}

// Round 10
// 6529.198 us; speedup vs baseline: 1.4238x; 1.4238x over previous
//
#include <hip/hip_runtime.h>

// Farthest Point Sampling: points (B, N, 3) fp32 -> indices (B, M) int32.
// B=16, N=65536, M=2048.  Reference semantics (locked in R2, absmax=0):
// float64 pipeline: dx=(double)x-(double)cx; d=((dx*dx+dy*dy)+dz*dz) with
// separate rounding (no FMA); min via fmin; argmax first-index tie-break
// (u64 bit-compare == f64 compare for nonneg values; verified R8).
//
// Round 10: shrink the exchange. Evidence chain: R9 (8 polling waves, 2x
// FETCH, +1.7 us/iter) + R4->R6 ladder => exchange cost ~ pollers x lines
// at the coherence point; R7 (XCD locality) and R8 (clocks) are neutral;
// R6's single-poller tail is right. So: BPB=8 x NT=1024 (128 blocks).
//   - poll load /4 (128 polling waves x 8 lines vs 256 x 16)
//   - barrier waits on 8 arrivals, not 16
//   - compute/CU 0.24 -> 0.48 us/iter (8192 pts/block, 96 KB LDS, PPT=8)
//   - R6 tail verbatim: one polling wave, s_c LDS broadcast, 2 syncs.
//
// Barrier protocol (R6, fence-free): 4 self-tagged 8-B relaxed atomic words
// per 128-B slot, per (parity, batch, rank):
//   A = value_lo32<<32 | m<<16 | idx        (idx<65536, m<2048: 16b each)
//   B = value_hi32<<32 | m<<16 | idx
//   C = x_bits<<32     | m<<16 | y_hi16
//   D = y_lo16<<48     | z_bits<<16 | m
// Aligned 8-B stores are single-copy atomic; every word carries m => torn
// epochs detected and re-polled. No fences => caches stay warm. Slot reuse
// (parity m&1): rewritten at m+2 only after its writer saw all tags m+1,
// which post only after every block read m. 0xAA poison tag = 0xAAAA != any
// m in [1,2048) => no init kernel.

#define N_PTS   65536
#define M_SAMP  2048
#define NT      1024
#define BPB     8                   // blocks per batch
#define PTS_BLK (N_PTS / BPB)       // 8192
#define PPT     (PTS_BLK / NT)      // 8 points per thread
#define NWAVES  (NT / 64)           // 16
#define NBATCH  16
#define SLOT_U64 16                 // 128 B per slot

typedef unsigned long long u64;

__device__ __forceinline__ u64 ld_agent(const u64* a) {
  return __hip_atomic_load(a, __ATOMIC_RELAXED, __HIP_MEMORY_SCOPE_AGENT);
}
__device__ __forceinline__ void st_agent(u64* a, u64 v) {
  __hip_atomic_store(a, v, __ATOMIC_RELAXED, __HIP_MEMORY_SCOPE_AGENT);
}

__global__ __launch_bounds__(NT)
void fps_multi(const float* __restrict__ pts, int* __restrict__ out,
               u64* __restrict__ ws) {
  const int rank = blockIdx.x & (BPB - 1);     // linear id = b*8 + rank
  const int b    = blockIdx.x >> 3;
  const float* __restrict__ p = pts + (size_t)b * (size_t)(N_PTS * 3);
  int* __restrict__ o = out + (size_t)b * M_SAMP;
  const int t = threadIdx.x;
  const int base = rank * PTS_BLK;

  __shared__ float s_pts[PTS_BLK * 3];         // 96 KB slice
  __shared__ u64   s_wv[NWAVES];               // per-wave winners
  __shared__ int   s_wi[NWAVES];
  __shared__ float s_c[3];                     // broadcast centroid coords
  __shared__ int   s_widx;

  for (int i = t; i < PTS_BLK * 3; i += NT)
    s_pts[i] = p[base * 3 + i];
  if (rank == 0 && t == 0) o[0] = 0;
  if (t == 0) { s_c[0] = p[0]; s_c[1] = p[1]; s_c[2] = p[2]; }  // seed pt 0
  __syncthreads();

  // Own points pre-converted to f64; (double)x is exact.
  double pd[PPT][3];
  double md[PPT];
#pragma unroll
  for (int j = 0; j < PPT; ++j) {
    const int l = t + j * NT;
    pd[j][0] = (double)s_pts[3 * l + 0];
    pd[j][1] = (double)s_pts[3 * l + 1];
    pd[j][2] = (double)s_pts[3 * l + 2];
    md[j] = 1e10;
  }

  for (int m = 1; m < M_SAMP; ++m) {
    const double cx = (double)s_c[0];
    const double cy = (double)s_c[1];
    const double cz = (double)s_c[2];

    u64 bestb = 0;              // loses to any d>0; ties at +0 resolved by idx
    int besti = base + t;

    // Indices base + t + j*NT ascend with j => strict '>' keeps the first
    // (lowest-index) maximum within a thread.
#pragma unroll
    for (int j = 0; j < PPT; ++j) {
      const double dx = __dsub_rn(pd[j][0], cx);
      const double dy = __dsub_rn(pd[j][1], cy);
      const double dz = __dsub_rn(pd[j][2], cz);
      const double d  = __dadd_rn(__dadd_rn(__dmul_rn(dx, dx),
                                            __dmul_rn(dy, dy)),
                                  __dmul_rn(dz, dz));
      const double nmd = fmin(md[j], d);
      md[j] = nmd;
      const u64 nb = (u64)__double_as_longlong(nmd);
      if (nb > bestb) { bestb = nb; besti = base + t + j * NT; }
    }

    // 64-lane butterfly argmax (u64 compare), min-index tie-break.
#pragma unroll
    for (int off = 32; off >= 1; off >>= 1) {
      const u64 ov = __shfl_xor(bestb, off, 64);
      const int oi = __shfl_xor(besti, off, 64);
      if (ov > bestb || (ov == bestb && oi < besti)) { bestb = ov; besti = oi; }
    }
    if ((t & 63) == 0) { s_wv[t >> 6] = bestb; s_wi[t >> 6] = besti; }
    __syncthreads();

    // Wave 0: reduce 16 wave winners, publish, poll 8 slots, reduce, share.
    if (t < 64) {
      if (t < NWAVES) { bestb = s_wv[t]; besti = s_wi[t]; }
      else            { bestb = 0;       besti = 0x7FFFFFFF; }
#pragma unroll
      for (int off = NWAVES / 2; off >= 1; off >>= 1) {
        const u64 ov = __shfl_xor(bestb, off, 64);
        const int oi = __shfl_xor(besti, off, 64);
        if (ov > bestb || (ov == bestb && oi < besti)) { bestb = ov; besti = oi; }
      }
      const u64 mm  = (u64)(unsigned)m;
      const u64 grp = (u64)((((m & 1) * NBATCH + b) * BPB));
      if (t == 0) {
        u64* slot = ws + (grp + rank) * SLOT_U64;
        const int l = besti - base;           // block winner lies in our slice
        const unsigned xb = __float_as_uint(s_pts[3 * l + 0]);
        const unsigned yb = __float_as_uint(s_pts[3 * l + 1]);
        const unsigned zb = __float_as_uint(s_pts[3 * l + 2]);
        const u64 ti = (mm << 16) | (u64)(unsigned)besti;
        st_agent(&slot[0], (bestb << 32) | ti);                       // A
        st_agent(&slot[1], (bestb & 0xFFFFFFFF00000000ull) | ti);     // B
        st_agent(&slot[2], ((u64)xb << 32) | (mm << 16) | (u64)(yb >> 16));        // C
        st_agent(&slot[3], ((u64)(yb & 0xFFFFu) << 48) | ((u64)zb << 16) | mm);    // D
      }
      if (t < BPB) {
        const u64* rs = ws + (grp + t) * SLOT_U64;
        u64 A, B, C, D;
        for (;;) {
          A = ld_agent(rs + 0);
          B = ld_agent(rs + 1);
          C = ld_agent(rs + 2);
          D = ld_agent(rs + 3);
          const bool ok = (((A >> 16) & 0xFFFFull) == mm) &
                          (((B >> 16) & 0xFFFFull) == mm) &
                          (((C >> 16) & 0xFFFFull) == mm) &
                          ((D & 0xFFFFull) == mm);
          if (ok) break;
        }
        u64 v = (B & 0xFFFFFFFF00000000ull) | (A >> 32);   // f64 bits
        int i = (int)(A & 0xFFFFull);
        float gx = __uint_as_float((unsigned)(C >> 32));
        float gy = __uint_as_float((unsigned)(((C & 0xFFFFull) << 16) | (D >> 48)));
        float gz = __uint_as_float((unsigned)((D >> 16) & 0xFFFFFFFFull));
        int r = t;                              // contributing rank
#pragma unroll
        for (int off = BPB / 2; off >= 1; off >>= 1) {
          const u64 ov = __shfl_xor(v, off, 64);
          const int oi = __shfl_xor(i, off, 64);
          const int orr = __shfl_xor(r, off, 64);
          if (ov > v || (ov == v && oi < i)) { v = ov; i = oi; r = orr; }
        }
        // Lanes 0..7 agree on winner rank r; pull its coords by shuffle.
        gx = __shfl(gx, r, 64);
        gy = __shfl(gy, r, 64);
        gz = __shfl(gz, r, 64);
        if (t == 0) {
          s_c[0] = gx; s_c[1] = gy; s_c[2] = gz;
          s_widx = i;
          if (rank == 0) o[m] = i;
        }
      }
    }
    __syncthreads();
    (void)s_widx;
  }
}

extern "C" void kernel_launch(void* const* d_in, const int* in_sizes, int n_in,
                              void* d_out, int out_size, void* d_ws, size_t ws_size,
                              hipStream_t stream) {
  const float* pts = (const float*)d_in[0];
  int* out = (int*)d_out;
  // ws usage: 2 * 16 * 8 slots * 128 B = 32 KB.
  hipLaunchKernelGGL(fps_multi, dim3(BPB * NBATCH), dim3(NT), 0, stream,
                     pts, out, (u64*)d_ws);
}

// Round 11
// 5858.877 us; speedup vs baseline: 1.5867x; 1.1144x over previous
//
#include <hip/hip_runtime.h>

// Farthest Point Sampling: points (B, N, 3) fp32 -> indices (B, M) int32.
// B=16, N=65536, M=2048.  Reference semantics (locked in R2, absmax=0):
// float64 pipeline: dx=(double)x-(double)cx; d=((dx*dx+dy*dy)+dz*dz) with
// separate rounding (no FMA); min via fmin; argmax first-index tie-break
// (u64 bit-compare == f64 compare for nonneg values; verified R8).
//
// Round 11: DPP reductions. Evidence: residual ~2.2 us/iter is the serial
// chain; costing with measured DS latencies (~120-130 cyc per dependent
// __shfl/ds stage x 13 stages) fully explains it. Replace all cross-lane
// reduction machinery with DPP (ALU-latency, ~5-15 cyc/stage):
//   - wave argmax: row_shr:1/2/4/8 + row_bcast15 + row_bcast31 -> lane 63
//   - 8-wave fold: row_shr:1/2/4 over lanes 0..7 -> lane 7
//   - 16-slot fold: row_shr:1/2/4/8 over lanes 0..15 -> lane 15
//   - broadcasts via v_readlane (winner rank = idx >> 12 since PTS_BLK=4096)
// Tie-break exact everywhere: compare (val_hi, val_lo) desc then idx asc.
// bound_ctrl=1 fakes are (0,0,0): they can only win folds whose true max
// is 0, and the block max is strictly >0 (4096 pts, <=2047 centroids,
// distinct gaussian points) => fakes never reach a published winner.
// Grid/config/protocol = R6 exactly (best known 5,836 us): dim3(16,16),
// NT=512, BPB=16, fence-free self-tagged 128-B slots, 2 barriers/iter.
//
// Slot protocol (R6): 4 self-tagged 8-B relaxed atomic words per slot,
// per (parity, batch, rank):
//   A = value_lo32<<32 | m<<16 | idx        (idx<65536, m<2048: 16b each)
//   B = value_hi32<<32 | m<<16 | idx
//   C = x_bits<<32     | m<<16 | y_hi16
//   D = y_lo16<<48     | z_bits<<16 | m
// Aligned 8-B stores are single-copy atomic; every word carries m => torn
// epochs detected and re-polled. No fences. Slot reuse (parity m&1):
// rewritten at m+2 only after its writer saw all tags m+1, which post only
// after every block read m. 0xAA poison tag != any m in [1,2048) => no init.

#define N_PTS   65536
#define M_SAMP  2048
#define NT      512
#define BPB     16                  // blocks per batch
#define PTS_BLK (N_PTS / BPB)       // 4096
#define PPT     (PTS_BLK / NT)      // 8 points per thread
#define NWAVES  (NT / 64)           // 8
#define NBATCH  16
#define SLOT_U64 16                 // 128 B per slot

typedef unsigned long long u64;

__device__ __forceinline__ u64 ld_agent(const u64* a) {
  return __hip_atomic_load(a, __ATOMIC_RELAXED, __HIP_MEMORY_SCOPE_AGENT);
}
__device__ __forceinline__ void st_agent(u64* a, u64 v) {
  __hip_atomic_store(a, v, __ATOMIC_RELAXED, __HIP_MEMORY_SCOPE_AGENT);
}

// DPP ctrl encodings (gfx9/CDNA): row_shr:N = 0x110+N, bcast15/31 = 0x142/3.
#define DPP_SHR1  0x111
#define DPP_SHR2  0x112
#define DPP_SHR4  0x114
#define DPP_SHR8  0x118
#define DPP_BC15  0x142
#define DPP_BC31  0x143

// One argmax fold stage via DPP: pull (hi,lo,idx) from the DPP-selected lane
// and keep the larger (value desc, then idx asc). bound_ctrl=1 -> invalid
// source lanes contribute (0,0,0), which loses to any positive value.
template <int CTRL>
__device__ __forceinline__ void dpp_fold(unsigned& hi, unsigned& lo, int& idx) {
  const unsigned nh = (unsigned)__builtin_amdgcn_update_dpp(0, (int)hi, CTRL, 0xF, 0xF, true);
  const unsigned nl = (unsigned)__builtin_amdgcn_update_dpp(0, (int)lo, CTRL, 0xF, 0xF, true);
  const int      ni = __builtin_amdgcn_update_dpp(0, idx,     CTRL, 0xF, 0xF, true);
  const bool take = (nh > hi) || ((nh == hi) && ((nl > lo) ||
                                  ((nl == lo) && (ni < idx))));
  if (take) { hi = nh; lo = nl; idx = ni; }
}

__global__ __launch_bounds__(NT, 2)
void fps_multi(const float* __restrict__ pts, int* __restrict__ out,
               u64* __restrict__ ws) {
  const int rank = blockIdx.x;                 // R6 grid: dim3(BPB, NBATCH)
  const int b    = blockIdx.y;
  const float* __restrict__ p = pts + (size_t)b * (size_t)(N_PTS * 3);
  int* __restrict__ o = out + (size_t)b * M_SAMP;
  const int t    = threadIdx.x;
  const int lane = t & 63;
  const int wave = t >> 6;
  const int base = rank * PTS_BLK;

  __shared__ float    s_pts[PTS_BLK * 3];      // 48 KB slice
  __shared__ unsigned s_wh[NWAVES];            // wave-winner value hi
  __shared__ unsigned s_wl[NWAVES];            // wave-winner value lo
  __shared__ int      s_wx[NWAVES];            // wave-winner idx
  __shared__ float    s_c[3];                  // centroid broadcast

  for (int i = t; i < PTS_BLK * 3; i += NT)
    s_pts[i] = p[base * 3 + i];
  if (rank == 0 && t == 0) o[0] = 0;
  if (t == 0) { s_c[0] = p[0]; s_c[1] = p[1]; s_c[2] = p[2]; }  // seed pt 0
  __syncthreads();

  // Own points pre-converted to f64; (double)x is exact.
  double pd[PPT][3];
  double md[PPT];
#pragma unroll
  for (int j = 0; j < PPT; ++j) {
    const int l = t + j * NT;
    pd[j][0] = (double)s_pts[3 * l + 0];
    pd[j][1] = (double)s_pts[3 * l + 1];
    pd[j][2] = (double)s_pts[3 * l + 2];
    md[j] = 1e10;
  }

  for (int m = 1; m < M_SAMP; ++m) {
    const double cx = (double)s_c[0];
    const double cy = (double)s_c[1];
    const double cz = (double)s_c[2];

    u64 bestb = 0;              // loses to any d>0; ties at +0 resolved by idx
    int besti = base + t;

    // Indices base + t + j*NT ascend with j => strict '>' keeps the first
    // (lowest-index) maximum within a thread.
#pragma unroll
    for (int j = 0; j < PPT; ++j) {
      const double dx = __dsub_rn(pd[j][0], cx);
      const double dy = __dsub_rn(pd[j][1], cy);
      const double dz = __dsub_rn(pd[j][2], cz);
      const double d  = __dadd_rn(__dadd_rn(__dmul_rn(dx, dx),
                                            __dmul_rn(dy, dy)),
                                  __dmul_rn(dz, dz));
      const double nmd = fmin(md[j], d);
      md[j] = nmd;
      const u64 nb = (u64)__double_as_longlong(nmd);
      if (nb > bestb) { bestb = nb; besti = base + t + j * NT; }
    }

    // Wave argmax via DPP scan-max: lane 63 ends with the wave winner.
    unsigned hi = (unsigned)(bestb >> 32), lo = (unsigned)bestb;
    dpp_fold<DPP_SHR1>(hi, lo, besti);
    dpp_fold<DPP_SHR2>(hi, lo, besti);
    dpp_fold<DPP_SHR4>(hi, lo, besti);
    dpp_fold<DPP_SHR8>(hi, lo, besti);
    dpp_fold<DPP_BC15>(hi, lo, besti);
    dpp_fold<DPP_BC31>(hi, lo, besti);
    if (lane == 63) { s_wh[wave] = hi; s_wl[wave] = lo; s_wx[wave] = besti; }
    __syncthreads();

    // Wave 0: fold 8 wave winners, publish, poll, fold 16 slots, share.
    if (t < 64) {
      unsigned fh = 0, fl = 0; int fi = 0;
      if (t < NWAVES) { fh = s_wh[t]; fl = s_wl[t]; fi = s_wx[t]; }
      dpp_fold<DPP_SHR1>(fh, fl, fi);
      dpp_fold<DPP_SHR2>(fh, fl, fi);
      dpp_fold<DPP_SHR4>(fh, fl, fi);
      // lane 7 = block winner; broadcast via readlane (SALU, fast).
      const unsigned bh = (unsigned)__builtin_amdgcn_readlane((int)fh, 7);
      const unsigned bl = (unsigned)__builtin_amdgcn_readlane((int)fl, 7);
      const int      bi = __builtin_amdgcn_readlane(fi, 7);

      const u64 mm  = (u64)(unsigned)m;
      const u64 grp = (u64)((((m & 1) * NBATCH + b) * BPB));
      if (t == 0) {
        u64* slot = ws + (grp + rank) * SLOT_U64;
        const int l = bi - base;              // block winner is in our slice
        const unsigned xb = __float_as_uint(s_pts[3 * l + 0]);
        const unsigned yb = __float_as_uint(s_pts[3 * l + 1]);
        const unsigned zb = __float_as_uint(s_pts[3 * l + 2]);
        const u64 bb = ((u64)bh << 32) | (u64)bl;
        const u64 ti = (mm << 16) | (u64)(unsigned)bi;
        st_agent(&slot[0], (bb << 32) | ti);                        // A
        st_agent(&slot[1], (bb & 0xFFFFFFFF00000000ull) | ti);      // B
        st_agent(&slot[2], ((u64)xb << 32) | (mm << 16) | (u64)(yb >> 16));        // C
        st_agent(&slot[3], ((u64)(yb & 0xFFFFu) << 48) | ((u64)zb << 16) | mm);    // D
      }

      unsigned ph = 0, pl = 0; int pi = 0;
      float gx = 0.0f, gy = 0.0f, gz = 0.0f;
      if (t < BPB) {
        const u64* rs = ws + (grp + t) * SLOT_U64;
        u64 A, B, C, D;
        for (;;) {
          A = ld_agent(rs + 0);
          B = ld_agent(rs + 1);
          C = ld_agent(rs + 2);
          D = ld_agent(rs + 3);
          const bool ok = (((A >> 16) & 0xFFFFull) == mm) &
                          (((B >> 16) & 0xFFFFull) == mm) &
                          (((C >> 16) & 0xFFFFull) == mm) &
                          ((D & 0xFFFFull) == mm);
          if (ok) break;
        }
        ph = (unsigned)(B >> 32);
        pl = (unsigned)(A >> 32);
        pi = (int)(A & 0xFFFFull);
        gx = __uint_as_float((unsigned)(C >> 32));
        gy = __uint_as_float((unsigned)(((C & 0xFFFFull) << 16) | (D >> 48)));
        gz = __uint_as_float((unsigned)((D >> 16) & 0xFFFFFFFFull));
      }
      // Fold the 16 rank winners (lanes >=16 hold losing (0,0,0)).
      dpp_fold<DPP_SHR1>(ph, pl, pi);
      dpp_fold<DPP_SHR2>(ph, pl, pi);
      dpp_fold<DPP_SHR4>(ph, pl, pi);
      dpp_fold<DPP_SHR8>(ph, pl, pi);
      // lane 15 = global winner; rank = idx >> 12 (PTS_BLK = 4096).
      const int wi = __builtin_amdgcn_readlane(pi, 15);
      const int wr = wi >> 12;
      const float cgx = __uint_as_float(
          (unsigned)__builtin_amdgcn_readlane((int)__float_as_uint(gx), wr));
      const float cgy = __uint_as_float(
          (unsigned)__builtin_amdgcn_readlane((int)__float_as_uint(gy), wr));
      const float cgz = __uint_as_float(
          (unsigned)__builtin_amdgcn_readlane((int)__float_as_uint(gz), wr));
      if (t == 0) {
        s_c[0] = cgx; s_c[1] = cgy; s_c[2] = cgz;
        if (rank == 0) o[m] = wi;
      }
    }
    __syncthreads();
  }
}

extern "C" void kernel_launch(void* const* d_in, const int* in_sizes, int n_in,
                              void* d_out, int out_size, void* d_ws, size_t ws_size,
                              hipStream_t stream) {
  const float* pts = (const float*)d_in[0];
  int* out = (int*)d_out;
  const int B = in_sizes[0] / (N_PTS * 3);   // 16
  // ws usage: 2 * 16 * 16 slots * 128 B = 64 KB.
  hipLaunchKernelGGL(fps_multi, dim3(BPB, B), dim3(NT), 0, stream,
                     pts, out, (u64*)d_ws);
}